// Round 3
// baseline (290.466 us; speedup 1.0000x reference)
//
#include <hip/hip_runtime.h>
#include <hip/hip_bf16.h>
#include <stdint.h>

// Problem constants
#define NFEAT 4096   // IN_FEATURES == OUT_FEATURES
#define MROWS 1024   // batch
// K (top-k) = 41, ALPHA_LR = 0.01, NUM_DYKSTRA_ITER = 50

typedef __bf16 bf16x8 __attribute__((ext_vector_type(8)));
typedef float  f32x4  __attribute__((ext_vector_type(4)));

__device__ __forceinline__ unsigned short bf16_rne(float f) {
    unsigned int u = __float_as_uint(f);
    unsigned int r = (u + 0x7fffu + ((u >> 16) & 1u)) >> 16;
    return (unsigned short)r;
}

// ---------------- Kernel 1: fused pre-pass ----------------
// block 0          : Dykstra soft top-k on alpha -> g (verified round-1 code)
// blocks 1..1024   : x fp32 -> bf16 (RNE) into xb, and zero out[] for the
//                    gemm's atomic-add epilogue. Fully hidden under dykstra.
__global__ __launch_bounds__(256) void pre_kernel(const float* __restrict__ alpha,
                                                  const float* __restrict__ x,
                                                  float* __restrict__ g,
                                                  unsigned short* __restrict__ xb,
                                                  float* __restrict__ outz) {
    __shared__ float red[4];
    const int tid = threadIdx.x;
    if (blockIdx.x == 0) {
        float y[16], p[16], q[16], yp[16];
        #pragma unroll
        for (int j = 0; j < 16; ++j) {
            y[j] = alpha[tid + 256 * j] / 0.01f;   // y0 = x / l
            p[j] = 0.0f;
            q[j] = 0.0f;
        }
        for (int it = 0; it < 50; ++it) {
            float s = 0.0f;
            #pragma unroll
            for (int j = 0; j < 16; ++j) { yp[j] = y[j] + p[j]; s += yp[j]; }
            #pragma unroll
            for (int off = 32; off > 0; off >>= 1) s += __shfl_down(s, off, 64);
            if ((tid & 63) == 0) red[tid >> 6] = s;
            __syncthreads();
            const float S = (red[0] + red[1]) + (red[2] + red[3]);
            __syncthreads();
            const float shift = (S - 41.0f) / 4096.0f;  // (sum - k) / n
            #pragma unroll
            for (int j = 0; j < 16; ++j) {
                float y_hp = yp[j] - shift;
                p[j] = yp[j] - y_hp;            // NOT folded to 'shift' (fp semantics)
                float yq = y_hp + q[j];
                float yb = fminf(fmaxf(yq, 0.0f), 1.0f);
                q[j] = yq - yb;
                y[j] = yb;
            }
        }
        #pragma unroll
        for (int j = 0; j < 16; ++j) g[tid + 256 * j] = y[j];
        return;
    }
    // cvt + zero: 1024 blocks x 256 threads x 16 elems
    const int b = blockIdx.x - 1;
    const size_t base = (size_t)b * 4096 + (size_t)tid * 16;
    float4 a0 = *(const float4*)(x + base);
    float4 a1 = *(const float4*)(x + base + 4);
    float4 a2 = *(const float4*)(x + base + 8);
    float4 a3 = *(const float4*)(x + base + 12);
    uint4 s0, s1;
    s0.x = bf16_rne(a0.x) | ((unsigned)bf16_rne(a0.y) << 16);
    s0.y = bf16_rne(a0.z) | ((unsigned)bf16_rne(a0.w) << 16);
    s0.z = bf16_rne(a1.x) | ((unsigned)bf16_rne(a1.y) << 16);
    s0.w = bf16_rne(a1.z) | ((unsigned)bf16_rne(a1.w) << 16);
    s1.x = bf16_rne(a2.x) | ((unsigned)bf16_rne(a2.y) << 16);
    s1.y = bf16_rne(a2.z) | ((unsigned)bf16_rne(a2.w) << 16);
    s1.z = bf16_rne(a3.x) | ((unsigned)bf16_rne(a3.y) << 16);
    s1.w = bf16_rne(a3.z) | ((unsigned)bf16_rne(a3.w) << 16);
    *(uint4*)(xb + base)     = s0;
    *(uint4*)(xb + base + 8) = s1;
    const float4 z = {0.f, 0.f, 0.f, 0.f};
    *(float4*)(outz + base)      = z;
    *(float4*)(outz + base + 4)  = z;
    *(float4*)(outz + base + 8)  = z;
    *(float4*)(outz + base + 12) = z;
}

// ---------------- Kernel 2: materialize W in bf16 ----------------
// W[r,c] = g[(r-c)%n] * V[(r-c)%n, c].  128(r) x 64(c) tile per block:
// band of 192 V rows in LDS (read amp 1.5 vs 2.0 for 64x64).
// Anti-diagonal LDS reads: addr delta per lane = -64+1 = -63 === 1 mod 32,
// conflict-free. Coalesced writes.
__global__ __launch_bounds__(256) void build_w_kernel(const float* __restrict__ V,
                                                      const float* __restrict__ g,
                                                      unsigned short* __restrict__ Wb) {
    __shared__ float vt[192 * 64];
    __shared__ float gl[192];
    const int tid = threadIdx.x;
    const int c0 = blockIdx.x * 64;
    const int r0 = blockIdx.y * 128;
    const int i0 = (r0 - c0 - 63) & 4095;
    #pragma unroll
    for (int j = 0; j < 12; ++j) {
        int idx = tid + 256 * j;        // 3072 float4 chunks = 192 rows x 16 float4
        int t   = idx >> 4;
        int col = (idx & 15) << 2;
        int i   = (i0 + t) & 4095;
        *(float4*)(vt + t * 64 + col) = *(const float4*)(V + (size_t)i * NFEAT + c0 + col);
    }
    if (tid < 192) gl[tid] = g[(i0 + tid) & 4095];
    __syncthreads();
    const int dc  = tid & 63;   // lane -> column (coalesced writes)
    const int drb = tid >> 6;
    #pragma unroll
    for (int j = 0; j < 32; ++j) {
        int dr = drb + 4 * j;                    // row within tile, uniform per wave
        int t  = dr - dc + 63;                   // in [0,190]
        float wv = gl[t] * vt[t * 64 + dc];
        Wb[(size_t)(r0 + dr) * NFEAT + c0 + dc] = bf16_rne(wv);
    }
}

// ---------------- Kernel 3: split-K GEMM, atomic-add epilogue ----------------
// A = xb (1024x4096 bf16), B = Wb (4096x4096 bf16 row-major = B^T), C fp32.
// 128x128 tile, BK=32, 256 threads = 4 waves (2x2), wave does 64x64 via 4x4
// mfma_f32_16x16x32_bf16. global_load_lds width=16, LDS [kgroup(4)][row(128)][8].
// S=8 K-slices: grid 32x8x8 = 2048 blocks = 8 blocks/CU = 32 waves/CU (max).
// Each slice unsafeAtomicAdd's its 128x128 fp32 tile into pre-zeroed out.
__global__ __launch_bounds__(256) void gemm_kernel(const unsigned short* __restrict__ A,
                                                   const unsigned short* __restrict__ B,
                                                   float* __restrict__ out) {
    __shared__ unsigned short As[4096];   // 8 KB
    __shared__ unsigned short Bs[4096];   // 8 KB
    const int tid  = threadIdx.x;
    const int lane = tid & 63;
    const int w    = tid >> 6;
    const int wm   = w & 1;
    const int wn   = w >> 1;
    const int m0   = blockIdx.y * 128;
    const int n0   = blockIdx.x * 128;
    const int kbase = blockIdx.z * 512;   // 16 k-iters x BK=32 per slice

    f32x4 acc[4][4];
    #pragma unroll
    for (int i = 0; i < 4; ++i)
        #pragma unroll
        for (int j = 0; j < 4; ++j)
            acc[i][j] = (f32x4){0.f, 0.f, 0.f, 0.f};

    const unsigned short* aS0 = A + (size_t)(m0 + lane) * NFEAT + kbase + w * 8;
    const unsigned short* aS1 = A + (size_t)(m0 + 64 + lane) * NFEAT + kbase + w * 8;
    const unsigned short* bS0 = B + (size_t)(n0 + lane) * NFEAT + kbase + w * 8;
    const unsigned short* bS1 = B + (size_t)(n0 + 64 + lane) * NFEAT + kbase + w * 8;
    unsigned short* aD0 = As + w * 1024;         // kg=w, rows 0..63
    unsigned short* aD1 = As + w * 1024 + 512;   // kg=w, rows 64..127
    unsigned short* bD0 = Bs + w * 1024;
    unsigned short* bD1 = Bs + w * 1024 + 512;

    const int kg = lane >> 4;
    const int lm = lane & 15;
    const unsigned short* aRd = As + kg * 1024 + (wm * 64 + lm) * 8;
    const unsigned short* bRd = Bs + kg * 1024 + (wn * 64 + lm) * 8;

    for (int kt = 0; kt < 16; ++kt) {
        const int ko = kt * 32;
        __syncthreads();
        __builtin_amdgcn_global_load_lds((__attribute__((address_space(1))) void*)(aS0 + ko),
                                         (__attribute__((address_space(3))) void*)aD0, 16, 0, 0);
        __builtin_amdgcn_global_load_lds((__attribute__((address_space(1))) void*)(aS1 + ko),
                                         (__attribute__((address_space(3))) void*)aD1, 16, 0, 0);
        __builtin_amdgcn_global_load_lds((__attribute__((address_space(1))) void*)(bS0 + ko),
                                         (__attribute__((address_space(3))) void*)bD0, 16, 0, 0);
        __builtin_amdgcn_global_load_lds((__attribute__((address_space(1))) void*)(bS1 + ko),
                                         (__attribute__((address_space(3))) void*)bD1, 16, 0, 0);
        __syncthreads();

        bf16x8 af[4], bfv[4];
        #pragma unroll
        for (int mi = 0; mi < 4; ++mi) af[mi]  = *(const bf16x8*)(aRd + mi * 128);
        #pragma unroll
        for (int ni = 0; ni < 4; ++ni) bfv[ni] = *(const bf16x8*)(bRd + ni * 128);
        #pragma unroll
        for (int mi = 0; mi < 4; ++mi)
            #pragma unroll
            for (int ni = 0; ni < 4; ++ni)
                acc[mi][ni] = __builtin_amdgcn_mfma_f32_16x16x32_bf16(af[mi], bfv[ni],
                                                                      acc[mi][ni], 0, 0, 0);
    }

    // C/D layout: col = lane&15, row = (lane>>4)*4 + reg  (m89-verified)
    const int crow = m0 + wm * 64 + (lane >> 4) * 4;
    const int ccol = n0 + wn * 64 + lm;
    #pragma unroll
    for (int mi = 0; mi < 4; ++mi)
        #pragma unroll
        for (int ni = 0; ni < 4; ++ni) {
            float* cp = out + (size_t)(crow + mi * 16) * NFEAT + ccol + ni * 16;
            #pragma unroll
            for (int r = 0; r < 4; ++r)
                unsafeAtomicAdd(cp + (size_t)r * NFEAT, acc[mi][ni][r]);
        }
}

extern "C" void kernel_launch(void* const* d_in, const int* in_sizes, int n_in,
                              void* d_out, int out_size, void* d_ws, size_t ws_size,
                              hipStream_t stream) {
    const float* x     = (const float*)d_in[0];   // (1024, 4096) fp32
    const float* V     = (const float*)d_in[1];   // (4096, 4096) fp32
    const float* alpha = (const float*)d_in[2];   // (4096,) fp32
    float* out = (float*)d_out;                   // (1024, 4096) fp32

    char* ws = (char*)d_ws;
    float* g           = (float*)ws;                                      // 16 KB
    unsigned short* xb = (unsigned short*)(ws + 16384);                   // 8 MB
    unsigned short* Wb = (unsigned short*)(ws + 16384 + (size_t)MROWS * NFEAT * 2); // 32 MB

    hipLaunchKernelGGL(pre_kernel,     dim3(1025),     dim3(256), 0, stream, alpha, x, g, xb, out);
    hipLaunchKernelGGL(build_w_kernel, dim3(64, 32),   dim3(256), 0, stream, V, g, Wb);
    hipLaunchKernelGGL(gemm_kernel,    dim3(32, 8, 8), dim3(256), 0, stream, xb, Wb, out);
}

// Round 4
// 252.600 us; speedup vs baseline: 1.1499x; 1.1499x over previous
//
#include <hip/hip_runtime.h>
#include <hip/hip_bf16.h>
#include <stdint.h>

// Problem constants
#define NFEAT 4096   // IN_FEATURES == OUT_FEATURES
#define MROWS 1024   // batch
// K (top-k) = 41, ALPHA_LR = 0.01, NUM_DYKSTRA_ITER = 50

typedef __bf16 bf16x8 __attribute__((ext_vector_type(8)));
typedef float  f32x4  __attribute__((ext_vector_type(4)));

__device__ __forceinline__ unsigned short bf16_rne(float f) {
    unsigned int u = __float_as_uint(f);
    unsigned int r = (u + 0x7fffu + ((u >> 16) & 1u)) >> 16;
    return (unsigned short)r;
}

// ---------------- Kernel 1: fused pre-pass ----------------
// block 0        : Dykstra soft top-k on alpha -> g (one barrier/iter via
//                  double-buffered red[]).
// blocks 1..1024 : x fp32 -> bf16 (RNE) into xb. Hidden under dykstra.
__global__ __launch_bounds__(256) void pre_kernel(const float* __restrict__ alpha,
                                                  const float* __restrict__ x,
                                                  float* __restrict__ g,
                                                  unsigned short* __restrict__ xb) {
    __shared__ float red[8];
    const int tid = threadIdx.x;
    if (blockIdx.x == 0) {
        float y[16], p[16], q[16], yp[16];
        #pragma unroll
        for (int j = 0; j < 16; ++j) {
            y[j] = alpha[tid + 256 * j] / 0.01f;   // y0 = x / l
            p[j] = 0.0f;
            q[j] = 0.0f;
        }
        for (int it = 0; it < 50; ++it) {
            float s = 0.0f;
            #pragma unroll
            for (int j = 0; j < 16; ++j) { yp[j] = y[j] + p[j]; s += yp[j]; }
            #pragma unroll
            for (int off = 32; off > 0; off >>= 1) s += __shfl_down(s, off, 64);
            const int half = (it & 1) * 4;          // WAR-safe double buffer
            if ((tid & 63) == 0) red[half + (tid >> 6)] = s;
            __syncthreads();
            const float S = (red[half] + red[half + 1]) + (red[half + 2] + red[half + 3]);
            const float shift = (S - 41.0f) / 4096.0f;  // (sum - k) / n
            #pragma unroll
            for (int j = 0; j < 16; ++j) {
                float y_hp = yp[j] - shift;
                p[j] = yp[j] - y_hp;            // NOT folded to 'shift' (fp semantics)
                float yq = y_hp + q[j];
                float yb = fminf(fmaxf(yq, 0.0f), 1.0f);
                q[j] = yq - yb;
                y[j] = yb;
            }
        }
        #pragma unroll
        for (int j = 0; j < 16; ++j) g[tid + 256 * j] = y[j];
        return;
    }
    // cvt: 1024 blocks x 256 threads x 16 elems
    const int b = blockIdx.x - 1;
    const size_t base = (size_t)b * 4096 + (size_t)tid * 16;
    float4 a0 = *(const float4*)(x + base);
    float4 a1 = *(const float4*)(x + base + 4);
    float4 a2 = *(const float4*)(x + base + 8);
    float4 a3 = *(const float4*)(x + base + 12);
    uint4 s0, s1;
    s0.x = bf16_rne(a0.x) | ((unsigned)bf16_rne(a0.y) << 16);
    s0.y = bf16_rne(a0.z) | ((unsigned)bf16_rne(a0.w) << 16);
    s0.z = bf16_rne(a1.x) | ((unsigned)bf16_rne(a1.y) << 16);
    s0.w = bf16_rne(a1.z) | ((unsigned)bf16_rne(a1.w) << 16);
    s1.x = bf16_rne(a2.x) | ((unsigned)bf16_rne(a2.y) << 16);
    s1.y = bf16_rne(a2.z) | ((unsigned)bf16_rne(a2.w) << 16);
    s1.z = bf16_rne(a3.x) | ((unsigned)bf16_rne(a3.y) << 16);
    s1.w = bf16_rne(a3.z) | ((unsigned)bf16_rne(a3.w) << 16);
    *(uint4*)(xb + base)     = s0;
    *(uint4*)(xb + base + 8) = s1;
}

// ---------------- Kernel 2: materialize W in bf16 ----------------
// W[r,c] = g[(r-c)%n] * V[(r-c)%n, c].  256(r) x 64(c) tile per block.
// The 319-row V band is premultiplied by g and stored bf16 in LDS (40 KB,
// read amp 1.25).  Write phase: 4 cols/thread, 8B stores; anti-diagonal 2B
// LDS reads have lane stride -504 B === 2 dwords mod 32 -> 2-way, free (m136).
__global__ __launch_bounds__(256) void build_w_kernel(const float* __restrict__ V,
                                                      const float* __restrict__ g,
                                                      unsigned short* __restrict__ Wb) {
    __shared__ unsigned short vb[319 * 64];   // 40 KB bf16, already *g
    const int tid = threadIdx.x;
    const int c0 = blockIdx.x * 64;
    const int r0 = blockIdx.y * 256;
    const int i0 = (r0 - c0 - 63) & 4095;
    // load band: 319 rows x 16 float4 = 5104 chunks
    #pragma unroll
    for (int j = 0; j < 20; ++j) {
        int idx = tid + 256 * j;
        if (idx < 5104) {
            int t   = idx >> 4;
            int col = (idx & 15) << 2;
            int i   = (i0 + t) & 4095;
            float gv = g[i];
            float4 v = *(const float4*)(V + (size_t)i * NFEAT + c0 + col);
            uint2 pk;
            pk.x = bf16_rne(v.x * gv) | ((unsigned)bf16_rne(v.y * gv) << 16);
            pk.y = bf16_rne(v.z * gv) | ((unsigned)bf16_rne(v.w * gv) << 16);
            *(uint2*)(vb + t * 64 + col) = pk;
        }
    }
    __syncthreads();
    const int dcp = tid & 15;       // col group: cols 4*dcp .. 4*dcp+3
    const int drb = tid >> 4;       // 16 rows per pass
    #pragma unroll
    for (int j = 0; j < 16; ++j) {
        int dr = drb + 16 * j;      // row within tile
        int c  = dcp * 4;
        int tb = dr - c + 63;       // in [3, 318]
        unsigned short w0 = vb[tb * 64 + c];
        unsigned short w1 = vb[(tb - 1) * 64 + c + 1];
        unsigned short w2 = vb[(tb - 2) * 64 + c + 2];
        unsigned short w3 = vb[(tb - 3) * 64 + c + 3];
        uint2 st;
        st.x = w0 | ((unsigned)w1 << 16);
        st.y = w2 | ((unsigned)w3 << 16);
        *(uint2*)(Wb + (size_t)(r0 + dr) * NFEAT + c0 + c) = st;
    }
}

// ---------------- Kernel 3: split-K GEMM (partials, no atomics) -------------
// A = xb (1024x4096 bf16), B = Wb (4096x4096 bf16 row-major = B^T), C fp32.
// 128(m) x 64(n) tile, BK=32, 256 threads = 4 waves along m (32 rows each,
// all 64 n-cols): acc 2x4 per wave. grid (64, 8, 4) = 2048 blocks = 8/CU for
// latency hiding (the round-2 bottleneck: Occ 33%, MfmaUtil 16%).
// Slice 0 writes d_out, slice s>0 writes Cp[s-1]; reduce sums them.
__global__ __launch_bounds__(256) void gemm_kernel(const unsigned short* __restrict__ A,
                                                   const unsigned short* __restrict__ B,
                                                   float* __restrict__ C0,
                                                   float* __restrict__ Cp) {
    __shared__ unsigned short As[4096];   // [kg(4)][row(128)][8]  8 KB
    __shared__ unsigned short Bs[2048];   // [kg(4)][row(64)][8]   4 KB
    const int tid  = threadIdx.x;
    const int lane = tid & 63;
    const int w    = tid >> 6;
    const int m0   = blockIdx.y * 128;
    const int n0   = blockIdx.x * 64;
    const int kbase = blockIdx.z * 1024;  // 32 k-iters x BK=32 per slice

    f32x4 acc[2][4];
    #pragma unroll
    for (int i = 0; i < 2; ++i)
        #pragma unroll
        for (int j = 0; j < 4; ++j)
            acc[i][j] = (f32x4){0.f, 0.f, 0.f, 0.f};

    const unsigned short* aS0 = A + (size_t)(m0 + lane) * NFEAT + kbase + w * 8;
    const unsigned short* aS1 = A + (size_t)(m0 + 64 + lane) * NFEAT + kbase + w * 8;
    const unsigned short* bS0 = B + (size_t)(n0 + lane) * NFEAT + kbase + w * 8;
    unsigned short* aD0 = As + w * 1024;         // kg=w, rows 0..63
    unsigned short* aD1 = As + w * 1024 + 512;   // kg=w, rows 64..127
    unsigned short* bD0 = Bs + w * 512;          // kg=w, rows 0..63

    const int kg = lane >> 4;
    const int lm = lane & 15;
    const unsigned short* aRd = As + kg * 1024 + (w * 32 + lm) * 8;
    const unsigned short* bRd = Bs + kg * 512 + lm * 8;

    for (int kt = 0; kt < 32; ++kt) {
        const int ko = kt * 32;
        __syncthreads();
        __builtin_amdgcn_global_load_lds((__attribute__((address_space(1))) void*)(aS0 + ko),
                                         (__attribute__((address_space(3))) void*)aD0, 16, 0, 0);
        __builtin_amdgcn_global_load_lds((__attribute__((address_space(1))) void*)(aS1 + ko),
                                         (__attribute__((address_space(3))) void*)aD1, 16, 0, 0);
        __builtin_amdgcn_global_load_lds((__attribute__((address_space(1))) void*)(bS0 + ko),
                                         (__attribute__((address_space(3))) void*)bD0, 16, 0, 0);
        __syncthreads();

        bf16x8 af[2], bfv[4];
        #pragma unroll
        for (int mi = 0; mi < 2; ++mi) af[mi]  = *(const bf16x8*)(aRd + mi * 128);
        #pragma unroll
        for (int ni = 0; ni < 4; ++ni) bfv[ni] = *(const bf16x8*)(bRd + ni * 128);
        #pragma unroll
        for (int mi = 0; mi < 2; ++mi)
            #pragma unroll
            for (int ni = 0; ni < 4; ++ni)
                acc[mi][ni] = __builtin_amdgcn_mfma_f32_16x16x32_bf16(af[mi], bfv[ni],
                                                                      acc[mi][ni], 0, 0, 0);
    }

    float* Cz = (blockIdx.z == 0) ? C0 : (Cp + (size_t)(blockIdx.z - 1) * MROWS * NFEAT);
    // C/D layout: col = lane&15, row = (lane>>4)*4 + reg  (m89-verified)
    const int crow = m0 + w * 32 + (lane >> 4) * 4;
    const int ccol = n0 + lm;
    #pragma unroll
    for (int mi = 0; mi < 2; ++mi)
        #pragma unroll
        for (int ni = 0; ni < 4; ++ni) {
            float* cp = Cz + (size_t)(crow + mi * 16) * NFEAT + ccol + ni * 16;
            #pragma unroll
            for (int r = 0; r < 4; ++r)
                cp[(size_t)r * NFEAT] = acc[mi][ni][r];
        }
}

// ---------------- Kernel 4: split-K reduce: out += sum of partials ----------
__global__ __launch_bounds__(256) void reduce_kernel(float* __restrict__ out,
                                                     const float* __restrict__ Cp) {
    const size_t i = (size_t)(blockIdx.x * 256 + threadIdx.x) * 4;
    float4 a = *(const float4*)(out + i);
    #pragma unroll
    for (int s = 0; s < 3; ++s) {
        float4 b = *(const float4*)(Cp + (size_t)s * MROWS * NFEAT + i);
        a.x += b.x; a.y += b.y; a.z += b.z; a.w += b.w;
    }
    *(float4*)(out + i) = a;
}

extern "C" void kernel_launch(void* const* d_in, const int* in_sizes, int n_in,
                              void* d_out, int out_size, void* d_ws, size_t ws_size,
                              hipStream_t stream) {
    const float* x     = (const float*)d_in[0];   // (1024, 4096) fp32
    const float* V     = (const float*)d_in[1];   // (4096, 4096) fp32
    const float* alpha = (const float*)d_in[2];   // (4096,) fp32
    float* out = (float*)d_out;                   // (1024, 4096) fp32

    char* ws = (char*)d_ws;
    float* g           = (float*)ws;                                            // 16 KB
    unsigned short* xb = (unsigned short*)(ws + 16384);                         // 8 MB
    unsigned short* Wb = (unsigned short*)(ws + 16384 + (size_t)MROWS * NFEAT * 2);
    float* Cp          = (float*)(ws + 16384 + (size_t)MROWS * NFEAT * 2
                                            + (size_t)NFEAT * NFEAT * 2);       // 48 MB partials

    hipLaunchKernelGGL(pre_kernel,     dim3(1025),     dim3(256), 0, stream, alpha, x, g, xb);
    hipLaunchKernelGGL(build_w_kernel, dim3(64, 16),   dim3(256), 0, stream, V, g, Wb);
    hipLaunchKernelGGL(gemm_kernel,    dim3(64, 8, 4), dim3(256), 0, stream, xb, Wb, out, Cp);
    hipLaunchKernelGGL(reduce_kernel,  dim3(MROWS * NFEAT / (256 * 4)), dim3(256), 0, stream,
                       out, Cp);
}

// Round 5
// 248.328 us; speedup vs baseline: 1.1697x; 1.0172x over previous
//
#include <hip/hip_runtime.h>
#include <hip/hip_bf16.h>
#include <stdint.h>

// Problem constants
#define NFEAT 4096   // IN_FEATURES == OUT_FEATURES
#define MROWS 1024   // batch
// K (top-k) = 41, ALPHA_LR = 0.01, NUM_DYKSTRA_ITER = 50

typedef __bf16 bf16x8 __attribute__((ext_vector_type(8)));
typedef float  f32x4  __attribute__((ext_vector_type(4)));

__device__ __forceinline__ unsigned short bf16_rne(float f) {
    unsigned int u = __float_as_uint(f);
    unsigned int r = (u + 0x7fffu + ((u >> 16) & 1u)) >> 16;
    return (unsigned short)r;
}

#define GLDS(src, dst) \
    __builtin_amdgcn_global_load_lds((__attribute__((address_space(1))) const void*)(src), \
                                     (__attribute__((address_space(3))) void*)(dst), 16, 0, 0)

// ---------------- Kernel 1: fused pre-pass ----------------
// block 0        : Dykstra soft top-k on alpha -> g (one barrier/iter,
//                  double-buffered red[]).
// blocks 1..1024 : x fp32 -> bf16 (RNE) into xb.
__global__ __launch_bounds__(256) void pre_kernel(const float* __restrict__ alpha,
                                                  const float* __restrict__ x,
                                                  float* __restrict__ g,
                                                  unsigned short* __restrict__ xb) {
    __shared__ float red[8];
    const int tid = threadIdx.x;
    if (blockIdx.x == 0) {
        float y[16], p[16], q[16], yp[16];
        #pragma unroll
        for (int j = 0; j < 16; ++j) {
            y[j] = alpha[tid + 256 * j] / 0.01f;   // y0 = x / l
            p[j] = 0.0f;
            q[j] = 0.0f;
        }
        for (int it = 0; it < 50; ++it) {
            float s = 0.0f;
            #pragma unroll
            for (int j = 0; j < 16; ++j) { yp[j] = y[j] + p[j]; s += yp[j]; }
            #pragma unroll
            for (int off = 32; off > 0; off >>= 1) s += __shfl_down(s, off, 64);
            const int half = (it & 1) * 4;          // WAR-safe double buffer
            if ((tid & 63) == 0) red[half + (tid >> 6)] = s;
            __syncthreads();
            const float S = (red[half] + red[half + 1]) + (red[half + 2] + red[half + 3]);
            const float shift = (S - 41.0f) / 4096.0f;  // (sum - k) / n
            #pragma unroll
            for (int j = 0; j < 16; ++j) {
                float y_hp = yp[j] - shift;
                p[j] = yp[j] - y_hp;            // NOT folded to 'shift' (fp semantics)
                float yq = y_hp + q[j];
                float yb = fminf(fmaxf(yq, 0.0f), 1.0f);
                q[j] = yq - yb;
                y[j] = yb;
            }
        }
        #pragma unroll
        for (int j = 0; j < 16; ++j) g[tid + 256 * j] = y[j];
        return;
    }
    // cvt: 1024 blocks x 256 threads x 16 elems
    const int b = blockIdx.x - 1;
    const size_t base = (size_t)b * 4096 + (size_t)tid * 16;
    float4 a0 = *(const float4*)(x + base);
    float4 a1 = *(const float4*)(x + base + 4);
    float4 a2 = *(const float4*)(x + base + 8);
    float4 a3 = *(const float4*)(x + base + 12);
    uint4 s0, s1;
    s0.x = bf16_rne(a0.x) | ((unsigned)bf16_rne(a0.y) << 16);
    s0.y = bf16_rne(a0.z) | ((unsigned)bf16_rne(a0.w) << 16);
    s0.z = bf16_rne(a1.x) | ((unsigned)bf16_rne(a1.y) << 16);
    s0.w = bf16_rne(a1.z) | ((unsigned)bf16_rne(a1.w) << 16);
    s1.x = bf16_rne(a2.x) | ((unsigned)bf16_rne(a2.y) << 16);
    s1.y = bf16_rne(a2.z) | ((unsigned)bf16_rne(a2.w) << 16);
    s1.z = bf16_rne(a3.x) | ((unsigned)bf16_rne(a3.y) << 16);
    s1.w = bf16_rne(a3.z) | ((unsigned)bf16_rne(a3.w) << 16);
    *(uint4*)(xb + base)     = s0;
    *(uint4*)(xb + base + 8) = s1;
}

// ---------------- Kernel 2: materialize W in bf16 ----------------
// W[r,c] = g[(r-c)%n] * V[(r-c)%n, c].  256(r) x 64(c) tile per block.
// 319-row V band premultiplied by g, stored bf16 in LDS (40 KB, amp 1.25).
// Write phase: 4 cols/thread, 8B stores; anti-diagonal 2B LDS reads stride
// -504 B === 2 dwords mod 32 -> 2-way aliasing, free (m136).
__global__ __launch_bounds__(256) void build_w_kernel(const float* __restrict__ V,
                                                      const float* __restrict__ g,
                                                      unsigned short* __restrict__ Wb) {
    __shared__ unsigned short vb[319 * 64];   // 40 KB bf16, already *g
    const int tid = threadIdx.x;
    const int c0 = blockIdx.x * 64;
    const int r0 = blockIdx.y * 256;
    const int i0 = (r0 - c0 - 63) & 4095;
    #pragma unroll
    for (int j = 0; j < 20; ++j) {
        int idx = tid + 256 * j;
        if (idx < 5104) {                     // 319 rows x 16 float4
            int t   = idx >> 4;
            int col = (idx & 15) << 2;
            int i   = (i0 + t) & 4095;
            float gv = g[i];
            float4 v = *(const float4*)(V + (size_t)i * NFEAT + c0 + col);
            uint2 pk;
            pk.x = bf16_rne(v.x * gv) | ((unsigned)bf16_rne(v.y * gv) << 16);
            pk.y = bf16_rne(v.z * gv) | ((unsigned)bf16_rne(v.w * gv) << 16);
            *(uint2*)(vb + t * 64 + col) = pk;
        }
    }
    __syncthreads();
    const int dcp = tid & 15;       // col group: cols 4*dcp .. 4*dcp+3
    const int drb = tid >> 4;       // 16 rows per pass
    #pragma unroll
    for (int j = 0; j < 16; ++j) {
        int dr = drb + 16 * j;
        int c  = dcp * 4;
        int tb = dr - c + 63;       // in [3, 318]
        unsigned short w0 = vb[tb * 64 + c];
        unsigned short w1 = vb[(tb - 1) * 64 + c + 1];
        unsigned short w2 = vb[(tb - 2) * 64 + c + 2];
        unsigned short w3 = vb[(tb - 3) * 64 + c + 3];
        uint2 st;
        st.x = w0 | ((unsigned)w1 << 16);
        st.y = w2 | ((unsigned)w3 << 16);
        *(uint2*)(Wb + (size_t)(r0 + dr) * NFEAT + c0 + c) = st;
    }
}

// ---------------- Kernel 3: split-K GEMM, BK=64 ----------------
// A = xb (1024x4096 bf16), B = Wb (4096x4096 bf16 row-major = B^T), C fp32.
// 128x128x64 tile: 32 KB LDS [kg(8)][row(128)][8], 4 waves (2x2) x 4x4 MFMA
// x 2 k-substeps = 32 MFMA per wave per barrier-drain (2x round 2, 4x round 4).
// Grid (32,8,S): S=8 -> 2048 blocks = 8/CU avail, ~4 resident (launch_bounds 4).
// Drains/CU = 8 blocks x 8 iters = 64 (vs 128 in r2, 256 in r4).
__global__ __launch_bounds__(256, 4) void gemm_kernel(const unsigned short* __restrict__ A,
                                                      const unsigned short* __restrict__ B,
                                                      float* __restrict__ C0,
                                                      float* __restrict__ Cp,
                                                      int kiters) {
    __shared__ unsigned short As[8192];   // [kg(8)][row(128)][8]  16 KB
    __shared__ unsigned short Bs[8192];   // 16 KB
    const int tid  = threadIdx.x;
    const int lane = tid & 63;
    const int w    = tid >> 6;
    const int wm   = w & 1;
    const int wn   = w >> 1;
    const int m0   = blockIdx.y * 128;
    const int n0   = blockIdx.x * 128;
    const int kbase = blockIdx.z * (kiters * 64);

    f32x4 acc[4][4];
    #pragma unroll
    for (int i = 0; i < 4; ++i)
        #pragma unroll
        for (int j = 0; j < 4; ++j)
            acc[i][j] = (f32x4){0.f, 0.f, 0.f, 0.f};

    // staging: thread covers kg in {w, w+4} x rowhalf in {0,64} for A and B
    const unsigned short* aS = A + (size_t)(m0 + lane) * NFEAT + kbase;
    const unsigned short* bS = B + (size_t)(n0 + lane) * NFEAT + kbase;

    const int kg4 = lane >> 4;
    const int lm  = lane & 15;
    const unsigned short* aRd = As + (wm * 64 + lm) * 8 + kg4 * 1024;
    const unsigned short* bRd = Bs + (wn * 64 + lm) * 8 + kg4 * 1024;

    for (int kt = 0; kt < kiters; ++kt) {
        const int ko = kt * 64;
        __syncthreads();
        GLDS(aS + ko + w * 8,                     As + w * 1024);
        GLDS(aS + ko + w * 8 + 64 * NFEAT,       As + w * 1024 + 512);
        GLDS(aS + ko + (w + 4) * 8,              As + (w + 4) * 1024);
        GLDS(aS + ko + (w + 4) * 8 + 64 * NFEAT, As + (w + 4) * 1024 + 512);
        GLDS(bS + ko + w * 8,                     Bs + w * 1024);
        GLDS(bS + ko + w * 8 + 64 * NFEAT,       Bs + w * 1024 + 512);
        GLDS(bS + ko + (w + 4) * 8,              Bs + (w + 4) * 1024);
        GLDS(bS + ko + (w + 4) * 8 + 64 * NFEAT, Bs + (w + 4) * 1024 + 512);
        __syncthreads();

        #pragma unroll
        for (int kk = 0; kk < 2; ++kk) {
            bf16x8 af[4], bfv[4];
            #pragma unroll
            for (int mi = 0; mi < 4; ++mi)
                af[mi]  = *(const bf16x8*)(aRd + kk * 4096 + mi * 128);
            #pragma unroll
            for (int ni = 0; ni < 4; ++ni)
                bfv[ni] = *(const bf16x8*)(bRd + kk * 4096 + ni * 128);
            #pragma unroll
            for (int mi = 0; mi < 4; ++mi)
                #pragma unroll
                for (int ni = 0; ni < 4; ++ni)
                    acc[mi][ni] = __builtin_amdgcn_mfma_f32_16x16x32_bf16(af[mi], bfv[ni],
                                                                          acc[mi][ni], 0, 0, 0);
        }
    }

    float* Cz = (blockIdx.z == 0) ? C0 : (Cp + (size_t)(blockIdx.z - 1) * MROWS * NFEAT);
    // C/D layout: col = lane&15, row = (lane>>4)*4 + reg  (m89-verified)
    const int crow = m0 + wm * 64 + (lane >> 4) * 4;
    const int ccol = n0 + wn * 64 + lm;
    #pragma unroll
    for (int mi = 0; mi < 4; ++mi)
        #pragma unroll
        for (int ni = 0; ni < 4; ++ni) {
            float* cp = Cz + (size_t)(crow + mi * 16) * NFEAT + ccol + ni * 16;
            #pragma unroll
            for (int r = 0; r < 4; ++r)
                cp[(size_t)r * NFEAT] = acc[mi][ni][r];
        }
}

// ---------------- Kernel 4: split-K reduce: out += sum of partials ----------
__global__ __launch_bounds__(256) void reduce_kernel(float* __restrict__ out,
                                                     const float* __restrict__ Cp,
                                                     int nparts) {
    const size_t i = (size_t)(blockIdx.x * 256 + threadIdx.x) * 4;
    float4 a = *(const float4*)(out + i);
    for (int s = 0; s < nparts; ++s) {
        float4 b = *(const float4*)(Cp + (size_t)s * MROWS * NFEAT + i);
        a.x += b.x; a.y += b.y; a.z += b.z; a.w += b.w;
    }
    *(float4*)(out + i) = a;
}

extern "C" void kernel_launch(void* const* d_in, const int* in_sizes, int n_in,
                              void* d_out, int out_size, void* d_ws, size_t ws_size,
                              hipStream_t stream) {
    const float* x     = (const float*)d_in[0];   // (1024, 4096) fp32
    const float* V     = (const float*)d_in[1];   // (4096, 4096) fp32
    const float* alpha = (const float*)d_in[2];   // (4096,) fp32
    float* out = (float*)d_out;                   // (1024, 4096) fp32

    char* ws = (char*)d_ws;
    const size_t xb_off = 16384;
    const size_t wb_off = xb_off + (size_t)MROWS * NFEAT * 2;   // + 8 MB
    const size_t cp_off = wb_off + (size_t)NFEAT * NFEAT * 2;   // +32 MB
    float* g           = (float*)ws;
    unsigned short* xb = (unsigned short*)(ws + xb_off);
    unsigned short* Wb = (unsigned short*)(ws + wb_off);
    float* Cp          = (float*)(ws + cp_off);

    const size_t part_bytes = (size_t)MROWS * NFEAT * 4;        // 16 MB each
    int S = (ws_size >= cp_off + 7 * part_bytes) ? 8 : 4;       // S=4 fits (r2-proven)
    const int kiters = 4096 / (64 * S);                         // 8 or 16

    hipLaunchKernelGGL(pre_kernel,     dim3(1025),     dim3(256), 0, stream, alpha, x, g, xb);
    hipLaunchKernelGGL(build_w_kernel, dim3(64, 16),   dim3(256), 0, stream, V, g, Wb);
    hipLaunchKernelGGL(gemm_kernel,    dim3(32, 8, S), dim3(256), 0, stream, xb, Wb, out, Cp, kiters);
    hipLaunchKernelGGL(reduce_kernel,  dim3(MROWS * NFEAT / (256 * 4)), dim3(256), 0, stream,
                       out, Cp, S - 1);
}

// Round 6
// 228.184 us; speedup vs baseline: 1.2729x; 1.0883x over previous
//
#include <hip/hip_runtime.h>
#include <hip/hip_bf16.h>
#include <stdint.h>

// Problem constants
#define NFEAT 4096   // IN_FEATURES == OUT_FEATURES
#define MROWS 1024   // batch
// K (top-k) = 41, ALPHA_LR = 0.01, NUM_DYKSTRA_ITER = 50

typedef __bf16 bf16x8 __attribute__((ext_vector_type(8)));
typedef float  f32x4  __attribute__((ext_vector_type(4)));

__device__ __forceinline__ unsigned short bf16_rne(float f) {
    unsigned int u = __float_as_uint(f);
    unsigned int r = (u + 0x7fffu + ((u >> 16) & 1u)) >> 16;
    return (unsigned short)r;
}

#define GLDS(src, dst) \
    __builtin_amdgcn_global_load_lds((__attribute__((address_space(1))) const void*)(src), \
                                     (__attribute__((address_space(3))) void*)(dst), 16, 0, 0)

// ---------------- Kernel 1: fused pre-pass ----------------
// block 0        : Dykstra soft top-k on alpha -> g (one barrier/iter,
//                  double-buffered red[]).
// blocks 1..1024 : x fp32 -> bf16 (RNE) into xb (hidden under dykstra).
__global__ __launch_bounds__(256) void pre_kernel(const float* __restrict__ alpha,
                                                  const float* __restrict__ x,
                                                  float* __restrict__ g,
                                                  unsigned short* __restrict__ xb) {
    __shared__ float red[8];
    const int tid = threadIdx.x;
    if (blockIdx.x == 0) {
        float y[16], p[16], q[16], yp[16];
        #pragma unroll
        for (int j = 0; j < 16; ++j) {
            y[j] = alpha[tid + 256 * j] / 0.01f;   // y0 = x / l
            p[j] = 0.0f;
            q[j] = 0.0f;
        }
        for (int it = 0; it < 50; ++it) {
            float s = 0.0f;
            #pragma unroll
            for (int j = 0; j < 16; ++j) { yp[j] = y[j] + p[j]; s += yp[j]; }
            #pragma unroll
            for (int off = 32; off > 0; off >>= 1) s += __shfl_down(s, off, 64);
            const int half = (it & 1) * 4;          // WAR-safe double buffer
            if ((tid & 63) == 0) red[half + (tid >> 6)] = s;
            __syncthreads();
            const float S = (red[half] + red[half + 1]) + (red[half + 2] + red[half + 3]);
            const float shift = (S - 41.0f) / 4096.0f;  // (sum - k) / n
            #pragma unroll
            for (int j = 0; j < 16; ++j) {
                float y_hp = yp[j] - shift;
                p[j] = yp[j] - y_hp;            // NOT folded to 'shift' (fp semantics)
                float yq = y_hp + q[j];
                float yb = fminf(fmaxf(yq, 0.0f), 1.0f);
                q[j] = yq - yb;
                y[j] = yb;
            }
        }
        #pragma unroll
        for (int j = 0; j < 16; ++j) g[tid + 256 * j] = y[j];
        return;
    }
    // cvt: 1024 blocks x 256 threads x 16 elems
    const int b = blockIdx.x - 1;
    const size_t base = (size_t)b * 4096 + (size_t)tid * 16;
    float4 a0 = *(const float4*)(x + base);
    float4 a1 = *(const float4*)(x + base + 4);
    float4 a2 = *(const float4*)(x + base + 8);
    float4 a3 = *(const float4*)(x + base + 12);
    uint4 s0, s1;
    s0.x = bf16_rne(a0.x) | ((unsigned)bf16_rne(a0.y) << 16);
    s0.y = bf16_rne(a0.z) | ((unsigned)bf16_rne(a0.w) << 16);
    s0.z = bf16_rne(a1.x) | ((unsigned)bf16_rne(a1.y) << 16);
    s0.w = bf16_rne(a1.z) | ((unsigned)bf16_rne(a1.w) << 16);
    s1.x = bf16_rne(a2.x) | ((unsigned)bf16_rne(a2.y) << 16);
    s1.y = bf16_rne(a2.z) | ((unsigned)bf16_rne(a2.w) << 16);
    s1.z = bf16_rne(a3.x) | ((unsigned)bf16_rne(a3.y) << 16);
    s1.w = bf16_rne(a3.z) | ((unsigned)bf16_rne(a3.w) << 16);
    *(uint4*)(xb + base)     = s0;
    *(uint4*)(xb + base + 8) = s1;
}

// ---------------- Kernel 2: materialize W in bf16 (r4-proven) ----------------
// W[r,c] = g[(r-c)%n] * V[(r-c)%n, c].  256(r) x 64(c) tile per block.
// 319-row V band premultiplied by g, stored bf16 in LDS (40 KB, amp 1.25).
__global__ __launch_bounds__(256) void build_w_kernel(const float* __restrict__ V,
                                                      const float* __restrict__ g,
                                                      unsigned short* __restrict__ Wb) {
    __shared__ unsigned short vb[319 * 64];   // 40 KB bf16, already *g
    const int tid = threadIdx.x;
    const int c0 = blockIdx.x * 64;
    const int r0 = blockIdx.y * 256;
    const int i0 = (r0 - c0 - 63) & 4095;
    #pragma unroll
    for (int j = 0; j < 20; ++j) {
        int idx = tid + 256 * j;
        if (idx < 5104) {                     // 319 rows x 16 float4
            int t   = idx >> 4;
            int col = (idx & 15) << 2;
            int i   = (i0 + t) & 4095;
            float gv = g[i];
            float4 v = *(const float4*)(V + (size_t)i * NFEAT + c0 + col);
            uint2 pk;
            pk.x = bf16_rne(v.x * gv) | ((unsigned)bf16_rne(v.y * gv) << 16);
            pk.y = bf16_rne(v.z * gv) | ((unsigned)bf16_rne(v.w * gv) << 16);
            *(uint2*)(vb + t * 64 + col) = pk;
        }
    }
    __syncthreads();
    const int dcp = tid & 15;       // col group: cols 4*dcp .. 4*dcp+3
    const int drb = tid >> 4;       // 16 rows per pass
    #pragma unroll
    for (int j = 0; j < 16; ++j) {
        int dr = drb + 16 * j;
        int c  = dcp * 4;
        int tb = dr - c + 63;       // in [3, 318]
        unsigned short w0 = vb[tb * 64 + c];
        unsigned short w1 = vb[(tb - 1) * 64 + c + 1];
        unsigned short w2 = vb[(tb - 2) * 64 + c + 2];
        unsigned short w3 = vb[(tb - 3) * 64 + c + 3];
        uint2 st;
        st.x = w0 | ((unsigned)w1 << 16);
        st.y = w2 | ((unsigned)w3 << 16);
        *(uint2*)(Wb + (size_t)(r0 + dr) * NFEAT + c0 + c) = st;
    }
}

// ---------------- Kernel 3: split-K GEMM, double-buffered LDS ----------------
// A = xb (1024x4096 bf16), B = Wb (4096x4096 bf16 row-major = B^T), C fp32.
// 128x128x32 tile, 2x(8+8) KB LDS dbuf. Per iter: barrier -> prefetch GLDS
// for tile kt+1 into buf[(kt+1)&1] -> MFMA from buf[kt&1]. The compiler's
// vmcnt(0)-before-barrier now drains loads that aged a full MFMA phase —
// the structural fix for the drain stall (r2/r4/r5 evidence).
// S=4: grid (32,8,4) = 1024 blocks = 4/CU resident (launch_bounds(256,4)).
__global__ __launch_bounds__(256, 4) void gemm_kernel(const unsigned short* __restrict__ A,
                                                      const unsigned short* __restrict__ B,
                                                      float* __restrict__ C0,
                                                      float* __restrict__ Cp,
                                                      int kiters) {
    __shared__ unsigned short As[2][4096];   // [buf][kg(4)][row(128)][8]  8 KB each
    __shared__ unsigned short Bs[2][4096];
    const int tid  = threadIdx.x;
    const int lane = tid & 63;
    const int w    = tid >> 6;
    const int wm   = w & 1;
    const int wn   = w >> 1;
    const int m0   = blockIdx.y * 128;
    const int n0   = blockIdx.x * 128;
    const int kbase = blockIdx.z * (kiters * 32);

    f32x4 acc[4][4];
    #pragma unroll
    for (int i = 0; i < 4; ++i)
        #pragma unroll
        for (int j = 0; j < 4; ++j)
            acc[i][j] = (f32x4){0.f, 0.f, 0.f, 0.f};

    const unsigned short* aS0 = A + (size_t)(m0 + lane) * NFEAT + kbase + w * 8;
    const unsigned short* aS1 = A + (size_t)(m0 + 64 + lane) * NFEAT + kbase + w * 8;
    const unsigned short* bS0 = B + (size_t)(n0 + lane) * NFEAT + kbase + w * 8;
    const unsigned short* bS1 = B + (size_t)(n0 + 64 + lane) * NFEAT + kbase + w * 8;

    // preload tile 0 into buf 0
    GLDS(aS0, As[0] + w * 1024);
    GLDS(aS1, As[0] + w * 1024 + 512);
    GLDS(bS0, Bs[0] + w * 1024);
    GLDS(bS1, Bs[0] + w * 1024 + 512);

    const int kg = lane >> 4;
    const int lm = lane & 15;
    const int aRdOff = kg * 1024 + (wm * 64 + lm) * 8;
    const int bRdOff = kg * 1024 + (wn * 64 + lm) * 8;

    for (int kt = 0; kt < kiters; ++kt) {
        __syncthreads();   // drains buf[kt&1] loads (issued last iter) + old ds_reads
        if (kt + 1 < kiters) {
            const int ko = (kt + 1) * 32;
            unsigned short* ad = As[(kt + 1) & 1] + w * 1024;
            unsigned short* bd = Bs[(kt + 1) & 1] + w * 1024;
            GLDS(aS0 + ko, ad);
            GLDS(aS1 + ko, ad + 512);
            GLDS(bS0 + ko, bd);
            GLDS(bS1 + ko, bd + 512);
        }
        const unsigned short* aRd = As[kt & 1] + aRdOff;
        const unsigned short* bRd = Bs[kt & 1] + bRdOff;
        bf16x8 af[4], bfv[4];
        #pragma unroll
        for (int mi = 0; mi < 4; ++mi) af[mi]  = *(const bf16x8*)(aRd + mi * 128);
        #pragma unroll
        for (int ni = 0; ni < 4; ++ni) bfv[ni] = *(const bf16x8*)(bRd + ni * 128);
        #pragma unroll
        for (int mi = 0; mi < 4; ++mi)
            #pragma unroll
            for (int ni = 0; ni < 4; ++ni)
                acc[mi][ni] = __builtin_amdgcn_mfma_f32_16x16x32_bf16(af[mi], bfv[ni],
                                                                      acc[mi][ni], 0, 0, 0);
    }

    float* Cz = (blockIdx.z == 0) ? C0 : (Cp + (size_t)(blockIdx.z - 1) * MROWS * NFEAT);
    // C/D layout: col = lane&15, row = (lane>>4)*4 + reg  (m89-verified)
    const int crow = m0 + wm * 64 + (lane >> 4) * 4;
    const int ccol = n0 + wn * 64 + lm;
    #pragma unroll
    for (int mi = 0; mi < 4; ++mi)
        #pragma unroll
        for (int ni = 0; ni < 4; ++ni) {
            float* cp = Cz + (size_t)(crow + mi * 16) * NFEAT + ccol + ni * 16;
            #pragma unroll
            for (int r = 0; r < 4; ++r)
                cp[(size_t)r * NFEAT] = acc[mi][ni][r];
        }
}

// ---------------- Kernel 4: split-K reduce: out += sum of partials ----------
__global__ __launch_bounds__(256) void reduce_kernel(float* __restrict__ out,
                                                     const float* __restrict__ Cp,
                                                     int nparts) {
    const size_t i = (size_t)(blockIdx.x * 256 + threadIdx.x) * 4;
    float4 a = *(const float4*)(out + i);
    for (int s = 0; s < nparts; ++s) {
        float4 b = *(const float4*)(Cp + (size_t)s * MROWS * NFEAT + i);
        a.x += b.x; a.y += b.y; a.z += b.z; a.w += b.w;
    }
    *(float4*)(out + i) = a;
}

extern "C" void kernel_launch(void* const* d_in, const int* in_sizes, int n_in,
                              void* d_out, int out_size, void* d_ws, size_t ws_size,
                              hipStream_t stream) {
    const float* x     = (const float*)d_in[0];   // (1024, 4096) fp32
    const float* V     = (const float*)d_in[1];   // (4096, 4096) fp32
    const float* alpha = (const float*)d_in[2];   // (4096,) fp32
    float* out = (float*)d_out;                   // (1024, 4096) fp32

    char* ws = (char*)d_ws;
    const size_t xb_off = 16384;
    const size_t wb_off = xb_off + (size_t)MROWS * NFEAT * 2;   // + 8 MB
    const size_t cp_off = wb_off + (size_t)NFEAT * NFEAT * 2;   // +32 MB
    float* g           = (float*)ws;
    unsigned short* xb = (unsigned short*)(ws + xb_off);
    unsigned short* Wb = (unsigned short*)(ws + wb_off);
    float* Cp          = (float*)(ws + cp_off);

    const size_t part_bytes = (size_t)MROWS * NFEAT * 4;        // 16 MB each
    int S = (ws_size >= cp_off + 3 * part_bytes) ? 4 : 2;       // S=4 proven to fit (r2/r5)
    const int kiters = 4096 / (32 * S);                         // 32 or 64

    hipLaunchKernelGGL(pre_kernel,     dim3(1025),     dim3(256), 0, stream, alpha, x, g, xb);
    hipLaunchKernelGGL(build_w_kernel, dim3(64, 16),   dim3(256), 0, stream, V, g, Wb);
    hipLaunchKernelGGL(gemm_kernel,    dim3(32, 8, S), dim3(256), 0, stream, xb, Wb, out, Cp, kiters);
    hipLaunchKernelGGL(reduce_kernel,  dim3(MROWS * NFEAT / (256 * 4)), dim3(256), 0, stream,
                       out, Cp, S - 1);
}

// Round 7
// 225.508 us; speedup vs baseline: 1.2880x; 1.0119x over previous
//
#include <hip/hip_runtime.h>
#include <hip/hip_bf16.h>
#include <stdint.h>

// Problem constants
#define NFEAT 4096   // IN_FEATURES == OUT_FEATURES
#define MROWS 1024   // batch
// K (top-k) = 41, ALPHA_LR = 0.01, NUM_DYKSTRA_ITER = 50

typedef __bf16 bf16x8 __attribute__((ext_vector_type(8)));
typedef float  f32x4  __attribute__((ext_vector_type(4)));

__device__ __forceinline__ unsigned short bf16_rne(float f) {
    unsigned int u = __float_as_uint(f);
    unsigned int r = (u + 0x7fffu + ((u >> 16) & 1u)) >> 16;
    return (unsigned short)r;
}

#define GLDS(src, dst) \
    __builtin_amdgcn_global_load_lds((__attribute__((address_space(1))) const void*)(src), \
                                     (__attribute__((address_space(3))) void*)(dst), 16, 0, 0)

// ---------------- Kernel 1: Dykstra soft top-k (1 block) ----------------
__global__ __launch_bounds__(256) void dykstra_kernel(const float* __restrict__ alpha,
                                                      float* __restrict__ g) {
    __shared__ float red[8];
    const int tid = threadIdx.x;
    float y[16], p[16], q[16], yp[16];
    #pragma unroll
    for (int j = 0; j < 16; ++j) {
        y[j] = alpha[tid + 256 * j] / 0.01f;   // y0 = x / l
        p[j] = 0.0f;
        q[j] = 0.0f;
    }
    for (int it = 0; it < 50; ++it) {
        float s = 0.0f;
        #pragma unroll
        for (int j = 0; j < 16; ++j) { yp[j] = y[j] + p[j]; s += yp[j]; }
        #pragma unroll
        for (int off = 32; off > 0; off >>= 1) s += __shfl_down(s, off, 64);
        const int half = (it & 1) * 4;          // WAR-safe double buffer
        if ((tid & 63) == 0) red[half + (tid >> 6)] = s;
        __syncthreads();
        const float S = (red[half] + red[half + 1]) + (red[half + 2] + red[half + 3]);
        const float shift = (S - 41.0f) / 4096.0f;  // (sum - k) / n
        #pragma unroll
        for (int j = 0; j < 16; ++j) {
            float y_hp = yp[j] - shift;
            p[j] = yp[j] - y_hp;            // NOT folded to 'shift' (fp semantics)
            float yq = y_hp + q[j];
            float yb = fminf(fmaxf(yq, 0.0f), 1.0f);
            q[j] = yq - yb;
            y[j] = yb;
        }
    }
    #pragma unroll
    for (int j = 0; j < 16; ++j) g[tid + 256 * j] = y[j];
}

// ---------------- Kernel 2: cvt x->bf16 + materialize W in bf16 -------------
// Each of 1024 blocks first converts its 16 KB slice of x, then builds a
// 256(r) x 64(c) tile of W[r,c] = g[(r-c)%n] * V[(r-c)%n, c].
// LDS band stride padded to 66 elems: write-phase anti-diagonal reads were
// 4-way bank-conflicted at stride 64 (drb step === 0 mod 32); at 66 they are
// <=2-way (free, m136).
__global__ __launch_bounds__(256) void build_w_kernel(const float* __restrict__ V,
                                                      const float* __restrict__ g,
                                                      const float* __restrict__ x,
                                                      unsigned short* __restrict__ xb,
                                                      unsigned short* __restrict__ Wb) {
    __shared__ unsigned short vb[319 * 66];   // ~42 KB bf16, already *g
    const int tid = threadIdx.x;
    const int bid = blockIdx.y * 64 + blockIdx.x;
    // --- cvt slice: 4096 floats per block ---
    {
        const size_t base = (size_t)bid * 4096 + (size_t)tid * 16;
        float4 a0 = *(const float4*)(x + base);
        float4 a1 = *(const float4*)(x + base + 4);
        float4 a2 = *(const float4*)(x + base + 8);
        float4 a3 = *(const float4*)(x + base + 12);
        uint4 s0, s1;
        s0.x = bf16_rne(a0.x) | ((unsigned)bf16_rne(a0.y) << 16);
        s0.y = bf16_rne(a0.z) | ((unsigned)bf16_rne(a0.w) << 16);
        s0.z = bf16_rne(a1.x) | ((unsigned)bf16_rne(a1.y) << 16);
        s0.w = bf16_rne(a1.z) | ((unsigned)bf16_rne(a1.w) << 16);
        s1.x = bf16_rne(a2.x) | ((unsigned)bf16_rne(a2.y) << 16);
        s1.y = bf16_rne(a2.z) | ((unsigned)bf16_rne(a2.w) << 16);
        s1.z = bf16_rne(a3.x) | ((unsigned)bf16_rne(a3.y) << 16);
        s1.w = bf16_rne(a3.z) | ((unsigned)bf16_rne(a3.w) << 16);
        *(uint4*)(xb + base)     = s0;
        *(uint4*)(xb + base + 8) = s1;
    }
    // --- band load: 319 rows x 16 float4, premultiplied by g ---
    const int c0 = blockIdx.x * 64;
    const int r0 = blockIdx.y * 256;
    const int i0 = (r0 - c0 - 63) & 4095;
    #pragma unroll
    for (int j = 0; j < 20; ++j) {
        int idx = tid + 256 * j;
        if (idx < 5104) {
            int t   = idx >> 4;
            int col = (idx & 15) << 2;
            int i   = (i0 + t) & 4095;
            float gv = g[i];
            float4 v = *(const float4*)(V + (size_t)i * NFEAT + c0 + col);
            uint2 pk;
            pk.x = bf16_rne(v.x * gv) | ((unsigned)bf16_rne(v.y * gv) << 16);
            pk.y = bf16_rne(v.z * gv) | ((unsigned)bf16_rne(v.w * gv) << 16);
            *(uint2*)(vb + t * 66 + col) = pk;
        }
    }
    __syncthreads();
    const int dcp = tid & 15;       // col group: cols 4*dcp .. 4*dcp+3
    const int drb = tid >> 4;       // 16 rows per pass
    #pragma unroll
    for (int j = 0; j < 16; ++j) {
        int dr = drb + 16 * j;
        int c  = dcp * 4;
        int tb = dr - c + 63;       // in [3, 318]
        unsigned short w0 = vb[tb * 66 + c];
        unsigned short w1 = vb[(tb - 1) * 66 + c + 1];
        unsigned short w2 = vb[(tb - 2) * 66 + c + 2];
        unsigned short w3 = vb[(tb - 3) * 66 + c + 3];
        uint2 st;
        st.x = w0 | ((unsigned)w1 << 16);
        st.y = w2 | ((unsigned)w3 << 16);
        *(uint2*)(Wb + (size_t)(r0 + dr) * NFEAT + c0 + c) = st;
    }
}

// ---------------- Kernel 3: split-K GEMM, 256x256x32, dbuf ----------------
// Staging-BW-bound regime (r2/r4/r5/r6 all ~6.5 TB/s staged): staged bytes =
// 8MB*(4096/Tn) + 32MB*(1024/Tm). 256x256 halves it to 256 MB vs 128^2.
// 512 threads = 8 waves (4m x 2n), wave = 64m x 128n, acc 4x8 f32x4.
// LDS [buf2][kg(4)][row(256)][8] for A and B = 64 KB total, dbuf prefetch.
// Grid (16,4,4) = 256 blocks = 1/CU; same-n0 blocks share an XCD (B slab 4 MB
// = L2-resident).
__global__ __launch_bounds__(512, 2) void gemm_kernel(const unsigned short* __restrict__ A,
                                                      const unsigned short* __restrict__ B,
                                                      float* __restrict__ C0,
                                                      float* __restrict__ Cp) {
    __shared__ unsigned short As[2][8192];   // 16 KB per buf
    __shared__ unsigned short Bs[2][8192];
    const int tid  = threadIdx.x;
    const int lane = tid & 63;
    const int w    = tid >> 6;       // 0..7
    const int wm   = w & 3;          // m strip (64 rows)
    const int wn   = w >> 2;         // n strip (128 cols)
    const int m0   = blockIdx.y * 256;
    const int n0   = blockIdx.x * 256;
    const int kbase = blockIdx.z * 1024;   // 32 iters x BK=32

    f32x4 acc[4][8];
    #pragma unroll
    for (int i = 0; i < 4; ++i)
        #pragma unroll
        for (int j = 0; j < 8; ++j)
            acc[i][j] = (f32x4){0.f, 0.f, 0.f, 0.f};

    // staging: wave w covers kg = w&3, row-quarters rq = (w>>2)*2 + {0,1}
    const int kgS = w & 3;
    const int rqB = (w >> 2) * 2;
    const unsigned short* aS = A + (size_t)(m0 + rqB * 64 + lane) * NFEAT + kbase + kgS * 8;
    const unsigned short* bS = B + (size_t)(n0 + rqB * 64 + lane) * NFEAT + kbase + kgS * 8;
    const int dOff = kgS * 2048 + rqB * 512;   // elems; +512 for second rq

    // preload tile 0 into buf 0
    GLDS(aS,                 As[0] + dOff);
    GLDS(aS + 64 * NFEAT,    As[0] + dOff + 512);
    GLDS(bS,                 Bs[0] + dOff);
    GLDS(bS + 64 * NFEAT,    Bs[0] + dOff + 512);

    const int kg4 = lane >> 4;
    const int lm  = lane & 15;
    const int aOff = kg4 * 2048 + (wm * 64 + lm) * 8;
    const int bOff = kg4 * 2048 + (wn * 128 + lm) * 8;

    for (int kt = 0; kt < 32; ++kt) {
        __syncthreads();   // vmcnt(0) drain: buf[kt&1] loads aged a full phase
        if (kt + 1 < 32) {
            const int ko = (kt + 1) * 32;
            const int nb = (kt + 1) & 1;
            GLDS(aS + ko,              As[nb] + dOff);
            GLDS(aS + ko + 64 * NFEAT, As[nb] + dOff + 512);
            GLDS(bS + ko,              Bs[nb] + dOff);
            GLDS(bS + ko + 64 * NFEAT, Bs[nb] + dOff + 512);
        }
        const unsigned short* aRd = As[kt & 1] + aOff;
        const unsigned short* bRd = Bs[kt & 1] + bOff;
        bf16x8 af[4], bfv[8];
        #pragma unroll
        for (int mi = 0; mi < 4; ++mi) af[mi]  = *(const bf16x8*)(aRd + mi * 128);
        #pragma unroll
        for (int ni = 0; ni < 8; ++ni) bfv[ni] = *(const bf16x8*)(bRd + ni * 128);
        #pragma unroll
        for (int mi = 0; mi < 4; ++mi)
            #pragma unroll
            for (int ni = 0; ni < 8; ++ni)
                acc[mi][ni] = __builtin_amdgcn_mfma_f32_16x16x32_bf16(af[mi], bfv[ni],
                                                                      acc[mi][ni], 0, 0, 0);
    }

    float* Cz = (blockIdx.z == 0) ? C0 : (Cp + (size_t)(blockIdx.z - 1) * MROWS * NFEAT);
    // C/D layout: col = lane&15, row = (lane>>4)*4 + reg  (m89-verified)
    const int crow = m0 + wm * 64 + (lane >> 4) * 4;
    const int ccol = n0 + wn * 128 + lm;
    #pragma unroll
    for (int mi = 0; mi < 4; ++mi)
        #pragma unroll
        for (int ni = 0; ni < 8; ++ni) {
            float* cp = Cz + (size_t)(crow + mi * 16) * NFEAT + ccol + ni * 16;
            #pragma unroll
            for (int r = 0; r < 4; ++r)
                cp[(size_t)r * NFEAT] = acc[mi][ni][r];
        }
}

// ---------------- Kernel 4: split-K reduce: out += sum of partials ----------
__global__ __launch_bounds__(256) void reduce_kernel(float* __restrict__ out,
                                                     const float* __restrict__ Cp) {
    const size_t i = (size_t)(blockIdx.x * 256 + threadIdx.x) * 4;
    float4 a = *(const float4*)(out + i);
    #pragma unroll
    for (int s = 0; s < 3; ++s) {
        float4 b = *(const float4*)(Cp + (size_t)s * MROWS * NFEAT + i);
        a.x += b.x; a.y += b.y; a.z += b.z; a.w += b.w;
    }
    *(float4*)(out + i) = a;
}

extern "C" void kernel_launch(void* const* d_in, const int* in_sizes, int n_in,
                              void* d_out, int out_size, void* d_ws, size_t ws_size,
                              hipStream_t stream) {
    const float* x     = (const float*)d_in[0];   // (1024, 4096) fp32
    const float* V     = (const float*)d_in[1];   // (4096, 4096) fp32
    const float* alpha = (const float*)d_in[2];   // (4096,) fp32
    float* out = (float*)d_out;                   // (1024, 4096) fp32

    char* ws = (char*)d_ws;
    const size_t xb_off = 16384;
    const size_t wb_off = xb_off + (size_t)MROWS * NFEAT * 2;   // + 8 MB
    const size_t cp_off = wb_off + (size_t)NFEAT * NFEAT * 2;   // +32 MB
    float* g           = (float*)ws;
    unsigned short* xb = (unsigned short*)(ws + xb_off);
    unsigned short* Wb = (unsigned short*)(ws + wb_off);
    float* Cp          = (float*)(ws + cp_off);                 // 48 MB (S=4)
    // ws_size >= 152 MB confirmed empirically (r5 ran S=8 = cp_off + 112 MB).

    hipLaunchKernelGGL(dykstra_kernel, dim3(1),        dim3(256), 0, stream, alpha, g);
    hipLaunchKernelGGL(build_w_kernel, dim3(64, 16),   dim3(256), 0, stream, V, g, x, xb, Wb);
    hipLaunchKernelGGL(gemm_kernel,    dim3(16, 4, 4), dim3(512), 0, stream, xb, Wb, out, Cp);
    hipLaunchKernelGGL(reduce_kernel,  dim3(MROWS * NFEAT / (256 * 4)), dim3(256), 0, stream,
                       out, Cp);
}